// Round 22
// baseline (116.659 us; speedup 1.0000x reference)
//
#include <hip/hip_runtime.h>
#include <math.h>

#define NUM_CLASSES 100000
#define EMB 512
#define BATCH 512

#define BNF 32                        /* classes per chunk */
#define NCHUNK (NUM_CLASSES / BNF)    /* 3125, exact — no tail */
#define NBC 128                       /* chunk columns */
#define GRID_F 256                    /* 2 row-groups x 128 cols */
#define RBLK 64                       /* k_red blocks, Q=2 */

// ArcFace constants (margin m=0.3, scale s=120)
#define S_SCALE 120.0f
#define COS_M   0.9553364891256061f
#define SIN_M   0.29552020666133955f
#define TH_C   (-0.9553364891256061f)
#define MM_C    0.08865606199840187f

typedef short bf8 __attribute__((ext_vector_type(8)));   // 8 x bf16
typedef float f4  __attribute__((ext_vector_type(4)));   // MFMA accumulator
typedef float f32x4 __attribute__((ext_vector_type(4)));

__device__ __forceinline__ unsigned short f2bf(float f) {
    union { float f; unsigned u; } a; a.f = f;
    unsigned r = a.u + 0x7fffu + ((a.u >> 16) & 1u);
    return (unsigned short)(r >> 16);
}

// ---------------------------------------------------------------------------
// k_pre: fused x-normalize (f32 -> bf16 xb) + exact target logits.
// ---------------------------------------------------------------------------
__global__ __launch_bounds__(256) void k_pre(const float* __restrict__ x,
                                             const float* __restrict__ W,
                                             const long long* __restrict__ label,
                                             unsigned short* __restrict__ xb,
                                             float* __restrict__ tcos,
                                             float* __restrict__ tphi) {
    int m    = blockIdx.x * 4 + (threadIdx.x >> 6);
    int lane = threadIdx.x & 63;
    int lb   = (int)label[m];
    const float4* xr = (const float4*)(x + (size_t)m  * EMB);
    const float4* wr = (const float4*)(W + (size_t)lb * EMB);
    float4 a = xr[lane * 2];
    float4 b = xr[lane * 2 + 1];
    float4 c = wr[lane * 2];
    float4 d = wr[lane * 2 + 1];
    float sx = a.x*a.x + a.y*a.y + a.z*a.z + a.w*a.w
             + b.x*b.x + b.y*b.y + b.z*b.z + b.w*b.w;
    float sw = c.x*c.x + c.y*c.y + c.z*c.z + c.w*c.w
             + d.x*d.x + d.y*d.y + d.z*d.z + d.w*d.w;
    float sd = a.x*c.x + a.y*c.y + a.z*c.z + a.w*c.w
             + b.x*d.x + b.y*d.y + b.z*d.z + b.w*d.w;
#pragma unroll
    for (int dd = 1; dd < 64; dd <<= 1) {
        sx += __shfl_xor(sx, dd);
        sw += __shfl_xor(sw, dd);
        sd += __shfl_xor(sd, dd);
    }
    float rnx = 1.0f / fmaxf(sqrtf(sx), 1e-12f);
    int4 o;
    o.x = f2bf(a.x * rnx) | (f2bf(a.y * rnx) << 16);
    o.y = f2bf(a.z * rnx) | (f2bf(a.w * rnx) << 16);
    o.z = f2bf(b.x * rnx) | (f2bf(b.y * rnx) << 16);
    o.w = f2bf(b.z * rnx) | (f2bf(b.w * rnx) << 16);
    ((int4*)(xb + (size_t)m * EMB))[lane] = o;
    if (lane == 0) {
        float cv = sd * rnx / fmaxf(sqrtf(sw), 1e-12f);
        float sine = sqrtf(fmaxf(0.f, 1.f - cv * cv));
        float phi  = cv * COS_M - sine * SIN_M;
        if (!(cv > TH_C)) phi = cv - MM_C;
        tcos[m] = S_SCALE * cv;
        tphi[m] = S_SCALE * phi;
    }
}

// ---------------------------------------------------------------------------
// k_fused: round-21 schedule, restructured to a PAIR-WISE pipeline:
//   4 x 32 KB LDS buffers, ONE barrier per TWO chunks.
//   Per pair (k, k+1): step(b0) | conv(b2)+load | step(b1) | conv(b3)+load
//   | [lgkm; barrier]. All four buffer indices distinct mod 4; the pair
//   barrier guarantees convs only overwrite buffers whose kloops finished
//   in the previous pair. Gains: half the barrier drains; chunk k's
//   epilogue (serial exp chain) overlaps chunk k+1's kloop.
// Locked: (512,2) 512-thread shape, A-pin, layouts, stagger wv&4.
// ---------------------------------------------------------------------------
__global__ __launch_bounds__(512, 2) void k_fused(
        const float* __restrict__ W, const unsigned short* __restrict__ xb,
        float2* __restrict__ pms) {
    __shared__ __align__(16) unsigned short Bb[4][BNF * EMB];  // 4 x 32 KiB

    const int tid  = threadIdx.x;
    const int lane = tid & 63;
    const int wv   = tid >> 6;                 // wave 0..7
    const int l15  = lane & 15;
    const int lg   = lane >> 4;
    const int bc   = (blockIdx.x & 7) | ((blockIdx.x >> 4) << 3);  // 0..127
    const int rg   = (blockIdx.x >> 3) & 1;                        // row group
    const int K    = (NCHUNK - bc + NBC - 1) / NBC;  // 24 or 25 chunks

    // A: rows rg*256 + wv*32 + {0,16} + l15, all K — loaded ONCE, pinned.
    const unsigned short* xp = xb + (size_t)(rg * 256 + wv * 32 + l15) * EMB;
    bf8 a0[16], a1[16];
#pragma unroll
    for (int ks = 0; ks < 16; ++ks) {
        a0[ks] = *(const bf8*)(xp + ks * 32 + lg * 8);
        a1[ks] = *(const bf8*)(xp + 16 * EMB + ks * 32 + lg * 8);
    }
#pragma unroll
    for (int ks = 0; ks < 16; ++ks) {
        asm volatile("" : "+v"(a0[ks]));       // pin: cannot be re-loaded
        asm volatile("" : "+v"(a1[ks]));
    }

    float Mr[2][4], Sr[2][4];
#pragma unroll
    for (int mf = 0; mf < 2; ++mf)
#pragma unroll
        for (int i = 0; i < 4; ++i) { Mr[mf][i] = -1e38f; Sr[mf][i] = 0.0f; }

    const char* Wbase = (const char*)W;
    f32x4 st[8];                                // staged f32 slab (32 VGPR)

    auto load_st = [&](int ci) {
        const char* src = Wbase + (size_t)ci * (BNF * EMB * 4)
                        + (wv * 4 + (lane >> 4)) * 2048 + (lane & 15) * 16;
#pragma unroll
        for (int q = 0; q < 8; ++q)
            st[q] = *(const f32x4*)(src + q * 256);
    };

    // convert slab in regs -> bb (swizzled bf16, S/||w|| folded)
    auto conv = [&](char* bb) {
        float sq = 0.0f;
#pragma unroll
        for (int q = 0; q < 8; ++q)
            sq += st[q][0]*st[q][0] + st[q][1]*st[q][1]
                + st[q][2]*st[q][2] + st[q][3]*st[q][3];
        sq += __shfl_xor(sq, 1); sq += __shfl_xor(sq, 2);
        sq += __shfl_xor(sq, 4); sq += __shfl_xor(sq, 8);   // 16-lane group
        float rn = S_SCALE * rsqrtf(fmaxf(sq, 1e-24f));
        const int cc = wv * 4 + (lane >> 4);   // class row 0..31
        const int i  = lane & 15;
#pragma unroll
        for (int q = 0; q < 8; ++q) {
            float v0 = st[q][0] * rn, v1 = st[q][1] * rn;
            float v2 = st[q][2] * rn, v3 = st[q][3] * rn;
            unsigned lo, hi;
            asm("v_cvt_pk_bf16_f32 %0, %1, %2" : "=v"(lo) : "v"(v0), "v"(v1));
            asm("v_cvt_pk_bf16_f32 %0, %1, %2" : "=v"(hi) : "v"(v2), "v"(v3));
            int fj = q * 8 + (i >> 1);                     // 16B unit 0..63
            int ad = cc * 1024 + ((fj ^ (cc & 7)) << 4) + ((i & 1) << 3);
            *(uint2*)(bb + ad) = make_uint2(lo, hi);
        }
    };

    // kloop + epilogue for one chunk held in buffer BB
    auto step = [&](const char* BB) {
        f4 acc00, acc01, acc10, acc11;
#pragma unroll
        for (int i = 0; i < 4; ++i) {
            acc00[i] = 0.0f; acc01[i] = 0.0f;
            acc10[i] = 0.0f; acc11[i] = 0.0f;
        }
#pragma unroll
        for (int ks = 0; ks < 16; ++ks) {
            int sx = (((ks * 4 + lg) ^ (l15 & 7)) << 4);
            bf8 b0 = *(const bf8*)(BB + l15 * 1024 + sx);
            bf8 b1 = *(const bf8*)(BB + (16 + l15) * 1024 + sx);
            acc00 = __builtin_amdgcn_mfma_f32_16x16x32_bf16(a0[ks], b0, acc00, 0, 0, 0);
            acc01 = __builtin_amdgcn_mfma_f32_16x16x32_bf16(a0[ks], b1, acc01, 0, 0, 0);
            acc10 = __builtin_amdgcn_mfma_f32_16x16x32_bf16(a1[ks], b0, acc10, 0, 0, 0);
            acc11 = __builtin_amdgcn_mfma_f32_16x16x32_bf16(a1[ks], b1, acc11, 0, 0, 0);
        }
#pragma unroll
        for (int i = 0; i < 4; ++i) {
            float v0 = acc00[i], v1 = acc01[i];
            float pm = fmaxf(v0, v1);
            float nM = fmaxf(Mr[0][i], pm);
            Sr[0][i] = Sr[0][i] * __expf(Mr[0][i] - nM)
                     + __expf(v0 - nM) + __expf(v1 - nM);
            Mr[0][i] = nM;
            float w0 = acc10[i], w1 = acc11[i];
            float qm = fmaxf(w0, w1);
            float nN = fmaxf(Mr[1][i], qm);
            Sr[1][i] = Sr[1][i] * __expf(Mr[1][i] - nN)
                     + __expf(w0 - nN) + __expf(w1 - nN);
            Mr[1][i] = nN;
        }
    };

    // ---- prologue: chunks 0,1 -> Bb[0],Bb[1]; chunk 2 -> regs ----
    load_st(bc);
    conv((char*)&Bb[0][0]);
    load_st(bc + NBC);                    // K >= 24 always
    conv((char*)&Bb[1][0]);
    if (K > 2) load_st(bc + 2 * NBC);
    asm volatile("s_waitcnt lgkmcnt(0)" ::: "memory");
    __builtin_amdgcn_sched_barrier(0);
    __builtin_amdgcn_s_barrier();
    __builtin_amdgcn_sched_barrier(0);

    int k = 0;
    for (; k + 1 < K; k += 2) {
        const int  p    = (k >> 1) & 1;
        char* B0 = (char*)&Bb[2 * p][0];
        char* B1 = (char*)&Bb[2 * p + 1][0];
        char* B2 = (char*)&Bb[2 * (1 - p)][0];
        char* B3 = (char*)&Bb[2 * (1 - p) + 1][0];
        const bool has2 = (k + 2) < K, has3 = (k + 3) < K, has4 = (k + 4) < K;
        const int  c3 = bc + (k + 3) * NBC, c4 = bc + (k + 4) * NBC;

        // stagger: wv&4 waves conv-first, others kloop-first
        if (wv & 4)   { if (has2) { conv(B2); if (has3) load_st(c3); } }
        step(B0);
        if (!(wv & 4)){ if (has2) { conv(B2); if (has3) load_st(c3); } }
        if (wv & 4)   { if (has3) { conv(B3); if (has4) load_st(c4); } }
        step(B1);
        if (!(wv & 4)){ if (has3) { conv(B3); if (has4) load_st(c4); } }

        asm volatile("s_waitcnt lgkmcnt(0)" ::: "memory");  // conv writes done
        __builtin_amdgcn_sched_barrier(0);
        __builtin_amdgcn_s_barrier();   // B2,B3 ready; B0,B1 consumed
        __builtin_amdgcn_sched_barrier(0);
    }
    if (k < K) {                         // odd tail (K=25): chunk k, no barrier
        const int p = (k >> 1) & 1;
        step((const char*)&Bb[2 * p][0]);
    }

    // ---- merge (M,S) across the 16 column-lanes, one write per row ----
#pragma unroll
    for (int mf = 0; mf < 2; ++mf)
#pragma unroll
        for (int i = 0; i < 4; ++i) {
            float M = Mr[mf][i], S = Sr[mf][i];
#pragma unroll
            for (int d = 1; d < 16; d <<= 1) {
                float oM = __shfl_xor(M, d), oS = __shfl_xor(S, d);
                float nM = fmaxf(M, oM);
                S = S * __expf(M - nM) + oS * __expf(oM - nM);
                M = nM;
            }
            if (l15 == 0) {
                int m = rg * 256 + wv * 32 + mf * 16 + lg * 4 + i;
                pms[(size_t)bc * BATCH + m] = make_float2(M, S);
            }
        }
}

// ---------------------------------------------------------------------------
// k_red: merge 2 column-partials per slot, coalesced. part[b][m].
// ---------------------------------------------------------------------------
__global__ __launch_bounds__(512) void k_red(const float2* __restrict__ pms,
                                             float2* __restrict__ part) {
    int t = threadIdx.x, b = blockIdx.x;
    float2 v0 = pms[(size_t)(b * 2)     * BATCH + t];
    float2 v1 = pms[(size_t)(b * 2 + 1) * BATCH + t];
    float M = fmaxf(v0.x, v1.x);
    float S = v0.y * __expf(v0.x - M) + v1.y * __expf(v1.x - M);
    part[b * BATCH + t] = make_float2(M, S);
}

// ---------------------------------------------------------------------------
// k_fin: merge 64 partials per row, patch label col, loss, mean.
// ---------------------------------------------------------------------------
__global__ __launch_bounds__(512) void k_fin(const float2* __restrict__ part,
                                             const float* __restrict__ tcos,
                                             const float* __restrict__ tphi,
                                             float* __restrict__ out) {
    int t = threadIdx.x;
    float M = -1e38f, S = 0.f;
#pragma unroll 4
    for (int b = 0; b < RBLK; ++b) {
        float2 v = part[b * BATCH + t];
        float nM = fmaxf(M, v.x);
        S = S * __expf(M - nM) + v.y * __expf(v.x - nM);
        M = nM;
    }
    float Sc = S - __expf(tcos[t] - M) + __expf(tphi[t] - M);
    Sc = fmaxf(Sc, 1e-30f);
    float loss = M + logf(Sc) - tphi[t];
#pragma unroll
    for (int d = 1; d < 64; d <<= 1) loss += __shfl_xor(loss, d);
    __shared__ float wred[8];
    if ((t & 63) == 0) wred[t >> 6] = loss;
    __syncthreads();
    if (t == 0) {
        float s = 0.f;
        for (int w = 0; w < 8; ++w) s += wred[w];
        out[0] = s / (float)BATCH;
    }
}

extern "C" void kernel_launch(void* const* d_in, const int* in_sizes, int n_in,
                              void* d_out, int out_size, void* d_ws, size_t ws_size,
                              hipStream_t stream) {
    const float*     x     = (const float*)d_in[0];
    const long long* label = (const long long*)d_in[1];
    const float*     W     = (const float*)d_in[2];
    float*           out   = (float*)d_out;

    // workspace layout (~1.4 MB)
    char* ws = (char*)d_ws;
    unsigned short* xb   = (unsigned short*)ws;              // 524288
    float*          tcos = (float*)(ws + 524288);            // 2048
    float*          tphi = (float*)(ws + 526336);            // 2048
    float2*         pms  = (float2*)(ws + 528384);           // 128*512*8 = 524288
    float2*         part = (float2*)(ws + 1052672);          // 64*512*8 = 262144

    k_pre  <<<BATCH / 4, 256, 0, stream>>>(x, W, label, xb, tcos, tphi);
    k_fused<<<GRID_F,    512, 0, stream>>>(W, xb, pms);
    k_red  <<<RBLK,      512, 0, stream>>>(pms, part);
    k_fin  <<<1,         512, 0, stream>>>(part, tcos, tphi, out);
}

// Round 23
// 93.313 us; speedup vs baseline: 1.2502x; 1.2502x over previous
//
#include <hip/hip_runtime.h>
#include <math.h>

#define NUM_CLASSES 100000
#define EMB 512
#define BATCH 512

#define BNF 32                        /* classes per chunk */
#define NCHUNK (NUM_CLASSES / BNF)    /* 3125, exact — no tail */
#define NBC 256                       /* chunk columns (was 128) */
#define GRID_F 512                    /* 2 row-groups x 256 cols, 2 blocks/CU */
#define RBLK 64                       /* k_red blocks, Q=4 */

// ArcFace constants (margin m=0.3, scale s=120)
#define S_SCALE 120.0f
#define COS_M   0.9553364891256061f
#define SIN_M   0.29552020666133955f
#define TH_C   (-0.9553364891256061f)
#define MM_C    0.08865606199840187f

typedef short bf8 __attribute__((ext_vector_type(8)));   // 8 x bf16
typedef float f4  __attribute__((ext_vector_type(4)));   // MFMA accumulator
typedef float f32x4 __attribute__((ext_vector_type(4)));

__device__ __forceinline__ unsigned short f2bf(float f) {
    union { float f; unsigned u; } a; a.f = f;
    unsigned r = a.u + 0x7fffu + ((a.u >> 16) & 1u);
    return (unsigned short)(r >> 16);
}

// ---------------------------------------------------------------------------
// k_pre: fused x-normalize (f32 -> bf16 xb) + exact target logits.
// ---------------------------------------------------------------------------
__global__ __launch_bounds__(256) void k_pre(const float* __restrict__ x,
                                             const float* __restrict__ W,
                                             const long long* __restrict__ label,
                                             unsigned short* __restrict__ xb,
                                             float* __restrict__ tcos,
                                             float* __restrict__ tphi) {
    int m    = blockIdx.x * 4 + (threadIdx.x >> 6);
    int lane = threadIdx.x & 63;
    int lb   = (int)label[m];
    const float4* xr = (const float4*)(x + (size_t)m  * EMB);
    const float4* wr = (const float4*)(W + (size_t)lb * EMB);
    float4 a = xr[lane * 2];
    float4 b = xr[lane * 2 + 1];
    float4 c = wr[lane * 2];
    float4 d = wr[lane * 2 + 1];
    float sx = a.x*a.x + a.y*a.y + a.z*a.z + a.w*a.w
             + b.x*b.x + b.y*b.y + b.z*b.z + b.w*b.w;
    float sw = c.x*c.x + c.y*c.y + c.z*c.z + c.w*c.w
             + d.x*d.x + d.y*d.y + d.z*d.z + d.w*d.w;
    float sd = a.x*c.x + a.y*c.y + a.z*c.z + a.w*c.w
             + b.x*d.x + b.y*d.y + b.z*d.z + b.w*d.w;
#pragma unroll
    for (int dd = 1; dd < 64; dd <<= 1) {
        sx += __shfl_xor(sx, dd);
        sw += __shfl_xor(sw, dd);
        sd += __shfl_xor(sd, dd);
    }
    float rnx = 1.0f / fmaxf(sqrtf(sx), 1e-12f);
    int4 o;
    o.x = f2bf(a.x * rnx) | (f2bf(a.y * rnx) << 16);
    o.y = f2bf(a.z * rnx) | (f2bf(a.w * rnx) << 16);
    o.z = f2bf(b.x * rnx) | (f2bf(b.y * rnx) << 16);
    o.w = f2bf(b.z * rnx) | (f2bf(b.w * rnx) << 16);
    ((int4*)(xb + (size_t)m * EMB))[lane] = o;
    if (lane == 0) {
        float cv = sd * rnx / fmaxf(sqrtf(sw), 1e-12f);
        float sine = sqrtf(fmaxf(0.f, 1.f - cv * cv));
        float phi  = cv * COS_M - sine * SIN_M;
        if (!(cv > TH_C)) phi = cv - MM_C;
        tcos[m] = S_SCALE * cv;
        tphi[m] = S_SCALE * phi;
    }
}

// ---------------------------------------------------------------------------
// k_fused: ROUND-18 k_fused VERBATIM (best, 84.3us) — only the GRID
// decomposition changed: NBC 128->256, grid 256->512 => 2 blocks/CU.
// Rationale: measured VGPR_Count 124-128 allows 4 waves/SIMD (m69), LDS
// 2x64KB fits; two co-resident blocks have INDEPENDENT barriers, so one
// block's lgkm-drain + epilogue overlaps the other's kloop — the r17 goal
// achieved WITHOUT touching the (512,2) shape that sets the reg budget.
// Per-column work halves (K=12-13 chunks).
// ---------------------------------------------------------------------------
__global__ __launch_bounds__(512, 2) void k_fused(
        const float* __restrict__ W, const unsigned short* __restrict__ xb,
        float2* __restrict__ pms) {
    __shared__ __align__(16) unsigned short Bb[2][BNF * EMB];  // 2 x 32 KiB

    const int tid  = threadIdx.x;
    const int lane = tid & 63;
    const int wv   = tid >> 6;                 // wave 0..7
    const int l15  = lane & 15;
    const int lg   = lane >> 4;
    const int bc   = (blockIdx.x & 7) | ((blockIdx.x >> 4) << 3);  // 0..255
    const int rg   = (blockIdx.x >> 3) & 1;                        // row group

    // A: rows rg*256 + wv*32 + {0,16} + l15, all K — loaded ONCE, pinned.
    const unsigned short* xp = xb + (size_t)(rg * 256 + wv * 32 + l15) * EMB;
    bf8 a0[16], a1[16];
#pragma unroll
    for (int ks = 0; ks < 16; ++ks) {
        a0[ks] = *(const bf8*)(xp + ks * 32 + lg * 8);
        a1[ks] = *(const bf8*)(xp + 16 * EMB + ks * 32 + lg * 8);
    }
#pragma unroll
    for (int ks = 0; ks < 16; ++ks) {
        asm volatile("" : "+v"(a0[ks]));       // pin: value now asm-defined,
        asm volatile("" : "+v"(a1[ks]));       // cannot be re-loaded from xb
    }

    float Mr[2][4], Sr[2][4];
#pragma unroll
    for (int mf = 0; mf < 2; ++mf)
#pragma unroll
        for (int i = 0; i < 4; ++i) { Mr[mf][i] = -1e38f; Sr[mf][i] = 0.0f; }

    const char* Wbase = (const char*)W;
    f32x4 st[8];                                // staged f32 slab (32 VGPR)

    // 16 lanes per class: lane (c = lane>>4, i = lane&15) holds the 32 f32
    // of class wv*4+c at class-byte offsets i*16 + q*256.
    auto load_st = [&](int ci) {
        const char* src = Wbase + (size_t)ci * (BNF * EMB * 4)
                        + (wv * 4 + (lane >> 4)) * 2048 + (lane & 15) * 16;
#pragma unroll
        for (int q = 0; q < 8; ++q)
            st[q] = *(const f32x4*)(src + q * 256);
    };

    // convert slab in regs -> Bb[b] (swizzled bf16, S/||w|| folded)
    auto conv = [&](int b) {
        float sq = 0.0f;
#pragma unroll
        for (int q = 0; q < 8; ++q)
            sq += st[q][0]*st[q][0] + st[q][1]*st[q][1]
                + st[q][2]*st[q][2] + st[q][3]*st[q][3];
        sq += __shfl_xor(sq, 1); sq += __shfl_xor(sq, 2);
        sq += __shfl_xor(sq, 4); sq += __shfl_xor(sq, 8);   // 16-lane group
        float rn = S_SCALE * rsqrtf(fmaxf(sq, 1e-24f));
        const int cc = wv * 4 + (lane >> 4);   // class row 0..31
        const int i  = lane & 15;
        char* bb = (char*)&Bb[b][0];
#pragma unroll
        for (int q = 0; q < 8; ++q) {
            float v0 = st[q][0] * rn, v1 = st[q][1] * rn;
            float v2 = st[q][2] * rn, v3 = st[q][3] * rn;
            unsigned lo, hi;
            asm("v_cvt_pk_bf16_f32 %0, %1, %2" : "=v"(lo) : "v"(v0), "v"(v1));
            asm("v_cvt_pk_bf16_f32 %0, %1, %2" : "=v"(hi) : "v"(v2), "v"(v3));
            int fj = q * 8 + (i >> 1);                     // 16B unit 0..63
            int ad = cc * 1024 + ((fj ^ (cc & 7)) << 4) + ((i & 1) << 3);
            *(uint2*)(bb + ad) = make_uint2(lo, hi);
        }
    };

    // ---- prologue: chunk bc -> Bb[0]; prefetch chunk bc+NBC into regs ----
    load_st(bc);
    conv(0);
    if (bc + NBC < NCHUNK) load_st(bc + NBC);
    asm volatile("s_waitcnt lgkmcnt(0)" ::: "memory");
    __builtin_amdgcn_sched_barrier(0);
    __builtin_amdgcn_s_barrier();
    __builtin_amdgcn_sched_barrier(0);

    int buf = 0;
    for (int ci = bc; ci < NCHUNK; ci += NBC) {
        const int  cn    = ci + NBC;
        const bool hasN  = cn < NCHUNK;
        const bool hasNN = cn + NBC < NCHUNK;

        f4 acc00, acc01, acc10, acc11;
#pragma unroll
        for (int i = 0; i < 4; ++i) {
            acc00[i] = 0.0f; acc01[i] = 0.0f;
            acc10[i] = 0.0f; acc11[i] = 0.0f;
        }
        const char* BB = (const char*)&Bb[buf][0];

        auto kloop = [&]() {
            __builtin_amdgcn_s_setprio(1);
#pragma unroll
            for (int ks = 0; ks < 16; ++ks) {
                int sx = (((ks * 4 + lg) ^ (l15 & 7)) << 4);
                bf8 b0 = *(const bf8*)(BB + l15 * 1024 + sx);
                bf8 b1 = *(const bf8*)(BB + (16 + l15) * 1024 + sx);
                acc00 = __builtin_amdgcn_mfma_f32_16x16x32_bf16(a0[ks], b0, acc00, 0, 0, 0);
                acc01 = __builtin_amdgcn_mfma_f32_16x16x32_bf16(a0[ks], b1, acc01, 0, 0, 0);
                acc10 = __builtin_amdgcn_mfma_f32_16x16x32_bf16(a1[ks], b0, acc10, 0, 0, 0);
                acc11 = __builtin_amdgcn_mfma_f32_16x16x32_bf16(a1[ks], b1, acc11, 0, 0, 0);
            }
            __builtin_amdgcn_s_setprio(0);
        };

        // ---- stagger: odd waves conv-first, even waves kloop-first ----
        if (wv & 1) {
            if (hasN) { conv(buf ^ 1); if (hasNN) load_st(cn + NBC); }
            kloop();
        } else {
            kloop();
            if (hasN) { conv(buf ^ 1); if (hasNN) load_st(cn + NBC); }
        }

        // ---- epilogue: logits ARE acc -> per-lane online (M,S) ----
#pragma unroll
        for (int i = 0; i < 4; ++i) {
            float v0 = acc00[i], v1 = acc01[i];
            float pm = fmaxf(v0, v1);
            float nM = fmaxf(Mr[0][i], pm);
            Sr[0][i] = Sr[0][i] * __expf(Mr[0][i] - nM)
                     + __expf(v0 - nM) + __expf(v1 - nM);
            Mr[0][i] = nM;
            float w0 = acc10[i], w1 = acc11[i];
            float qm = fmaxf(w0, w1);
            float nN = fmaxf(Mr[1][i], qm);
            Sr[1][i] = Sr[1][i] * __expf(Mr[1][i] - nN)
                     + __expf(w0 - nN) + __expf(w1 - nN);
            Mr[1][i] = nN;
        }

        asm volatile("s_waitcnt lgkmcnt(0)" ::: "memory");  // conv writes done
        __builtin_amdgcn_sched_barrier(0);
        __builtin_amdgcn_s_barrier();       // Bb[buf^1] ready, Bb[buf] consumed
        __builtin_amdgcn_sched_barrier(0);
        buf ^= 1;
    }

    // ---- merge (M,S) across the 16 column-lanes, one write per row ----
#pragma unroll
    for (int mf = 0; mf < 2; ++mf)
#pragma unroll
        for (int i = 0; i < 4; ++i) {
            float M = Mr[mf][i], S = Sr[mf][i];
#pragma unroll
            for (int d = 1; d < 16; d <<= 1) {
                float oM = __shfl_xor(M, d), oS = __shfl_xor(S, d);
                float nM = fmaxf(M, oM);
                S = S * __expf(M - nM) + oS * __expf(oM - nM);
                M = nM;
            }
            if (l15 == 0) {
                int m = rg * 256 + wv * 32 + mf * 16 + lg * 4 + i;
                pms[(size_t)bc * BATCH + m] = make_float2(M, S);
            }
        }
}

// ---------------------------------------------------------------------------
// k_red: merge 4 column-partials per slot, coalesced. part[b][m].
// ---------------------------------------------------------------------------
__global__ __launch_bounds__(512) void k_red(const float2* __restrict__ pms,
                                             float2* __restrict__ part) {
    int t = threadIdx.x, b = blockIdx.x;
    float M = -1e38f, S = 0.f;
#pragma unroll
    for (int q = 0; q < NBC / RBLK; ++q) {
        float2 v = pms[(size_t)(b * (NBC / RBLK) + q) * BATCH + t];
        float nM = fmaxf(M, v.x);
        S = S * __expf(M - nM) + v.y * __expf(v.x - nM);
        M = nM;
    }
    part[b * BATCH + t] = make_float2(M, S);
}

// ---------------------------------------------------------------------------
// k_fin: merge 64 partials per row, patch label col, loss, mean.
// ---------------------------------------------------------------------------
__global__ __launch_bounds__(512) void k_fin(const float2* __restrict__ part,
                                             const float* __restrict__ tcos,
                                             const float* __restrict__ tphi,
                                             float* __restrict__ out) {
    int t = threadIdx.x;
    float M = -1e38f, S = 0.f;
#pragma unroll 4
    for (int b = 0; b < RBLK; ++b) {
        float2 v = part[b * BATCH + t];
        float nM = fmaxf(M, v.x);
        S = S * __expf(M - nM) + v.y * __expf(v.x - nM);
        M = nM;
    }
    float Sc = S - __expf(tcos[t] - M) + __expf(tphi[t] - M);
    Sc = fmaxf(Sc, 1e-30f);
    float loss = M + logf(Sc) - tphi[t];
#pragma unroll
    for (int d = 1; d < 64; d <<= 1) loss += __shfl_xor(loss, d);
    __shared__ float wred[8];
    if ((t & 63) == 0) wred[t >> 6] = loss;
    __syncthreads();
    if (t == 0) {
        float s = 0.f;
        for (int w = 0; w < 8; ++w) s += wred[w];
        out[0] = s / (float)BATCH;
    }
}

extern "C" void kernel_launch(void* const* d_in, const int* in_sizes, int n_in,
                              void* d_out, int out_size, void* d_ws, size_t ws_size,
                              hipStream_t stream) {
    const float*     x     = (const float*)d_in[0];
    const long long* label = (const long long*)d_in[1];
    const float*     W     = (const float*)d_in[2];
    float*           out   = (float*)d_out;

    // workspace layout (~1.8 MB)
    char* ws = (char*)d_ws;
    unsigned short* xb   = (unsigned short*)ws;              // 524288
    float*          tcos = (float*)(ws + 524288);            // 2048
    float*          tphi = (float*)(ws + 526336);            // 2048
    float2*         pms  = (float2*)(ws + 528384);           // 256*512*8 = 1048576
    float2*         part = (float2*)(ws + 1576960);          // 64*512*8 = 262144

    k_pre  <<<BATCH / 4, 256, 0, stream>>>(x, W, label, xb, tcos, tphi);
    k_fused<<<GRID_F,    512, 0, stream>>>(W, xb, pms);
    k_red  <<<RBLK,      512, 0, stream>>>(pms, part);
    k_fin  <<<1,         512, 0, stream>>>(part, tcos, tphi, out);
}

// Round 24
// 83.609 us; speedup vs baseline: 1.3953x; 1.1161x over previous
//
#include <hip/hip_runtime.h>
#include <math.h>

#define NUM_CLASSES 100000
#define EMB 512
#define BATCH 512

#define BNF 32                        /* classes per chunk */
#define NCHUNK (NUM_CLASSES / BNF)    /* 3125, exact — no tail */
#define NBC 128                       /* chunk columns */
#define GRID_F 256                    /* 2 row-groups x 128 cols */
#define RBLK 64                       /* k_red blocks, Q=2 */

// ArcFace constants (margin m=0.3, scale s=120)
#define S_SCALE 120.0f
#define COS_M   0.9553364891256061f
#define SIN_M   0.29552020666133955f
#define TH_C   (-0.9553364891256061f)
#define MM_C    0.08865606199840187f

typedef short bf8 __attribute__((ext_vector_type(8)));   // 8 x bf16
typedef float f4  __attribute__((ext_vector_type(4)));   // MFMA accumulator
typedef float f32x4 __attribute__((ext_vector_type(4)));

__device__ __forceinline__ unsigned short f2bf(float f) {
    union { float f; unsigned u; } a; a.f = f;
    unsigned r = a.u + 0x7fffu + ((a.u >> 16) & 1u);
    return (unsigned short)(r >> 16);
}

// ---------------------------------------------------------------------------
// k_pre: fused x-normalize (f32 -> bf16 xb) + exact target logits.
// 128 blocks x 256 threads; wave handles row m = blk*4 + (tid>>6).
// ---------------------------------------------------------------------------
__global__ __launch_bounds__(256) void k_pre(const float* __restrict__ x,
                                             const float* __restrict__ W,
                                             const long long* __restrict__ label,
                                             unsigned short* __restrict__ xb,
                                             float* __restrict__ tcos,
                                             float* __restrict__ tphi) {
    int m    = blockIdx.x * 4 + (threadIdx.x >> 6);
    int lane = threadIdx.x & 63;
    int lb   = (int)label[m];
    const float4* xr = (const float4*)(x + (size_t)m  * EMB);
    const float4* wr = (const float4*)(W + (size_t)lb * EMB);
    float4 a = xr[lane * 2];
    float4 b = xr[lane * 2 + 1];
    float4 c = wr[lane * 2];
    float4 d = wr[lane * 2 + 1];
    float sx = a.x*a.x + a.y*a.y + a.z*a.z + a.w*a.w
             + b.x*b.x + b.y*b.y + b.z*b.z + b.w*b.w;
    float sw = c.x*c.x + c.y*c.y + c.z*c.z + c.w*c.w
             + d.x*d.x + d.y*d.y + d.z*d.z + d.w*d.w;
    float sd = a.x*c.x + a.y*c.y + a.z*c.z + a.w*c.w
             + b.x*d.x + b.y*d.y + b.z*d.z + b.w*d.w;
#pragma unroll
    for (int dd = 1; dd < 64; dd <<= 1) {
        sx += __shfl_xor(sx, dd);
        sw += __shfl_xor(sw, dd);
        sd += __shfl_xor(sd, dd);
    }
    float rnx = 1.0f / fmaxf(sqrtf(sx), 1e-12f);
    int4 o;
    o.x = f2bf(a.x * rnx) | (f2bf(a.y * rnx) << 16);
    o.y = f2bf(a.z * rnx) | (f2bf(a.w * rnx) << 16);
    o.z = f2bf(b.x * rnx) | (f2bf(b.y * rnx) << 16);
    o.w = f2bf(b.z * rnx) | (f2bf(b.w * rnx) << 16);
    ((int4*)(xb + (size_t)m * EMB))[lane] = o;
    if (lane == 0) {
        float cv = sd * rnx / fmaxf(sqrtf(sw), 1e-12f);
        float sine = sqrtf(fmaxf(0.f, 1.f - cv * cv));
        float phi  = cv * COS_M - sine * SIN_M;
        if (!(cv > TH_C)) phi = cv - MM_C;
        tcos[m] = S_SCALE * cv;
        tphi[m] = S_SCALE * phi;
    }
}

// ---------------------------------------------------------------------------
// k_fused: ROUND-18 VERBATIM — the best verified configuration (84.3 us).
// Probe ledger (all isolated): stagger wv&4 neutral; T13-lite regress;
// setprio-removal neutral; 2-chunk pipeline regress (spills); 256-thr
// blocks regress (128-reg budget); 2 blocks/CU grid regress (2x W/CU).
// (512,2) 512-thread shape is LOCKED: the only config with a >=200-reg
// budget that holds st[8] + pinned A without spilling.
// ---------------------------------------------------------------------------
__global__ __launch_bounds__(512, 2) void k_fused(
        const float* __restrict__ W, const unsigned short* __restrict__ xb,
        float2* __restrict__ pms) {
    __shared__ __align__(16) unsigned short Bb[2][BNF * EMB];  // 2 x 32 KiB

    const int tid  = threadIdx.x;
    const int lane = tid & 63;
    const int wv   = tid >> 6;                 // wave 0..7
    const int l15  = lane & 15;
    const int lg   = lane >> 4;
    const int bc   = (blockIdx.x & 7) | ((blockIdx.x >> 4) << 3);  // 0..127
    const int rg   = (blockIdx.x >> 3) & 1;                        // row group

    // A: rows rg*256 + wv*32 + {0,16} + l15, all K — loaded ONCE, pinned.
    const unsigned short* xp = xb + (size_t)(rg * 256 + wv * 32 + l15) * EMB;
    bf8 a0[16], a1[16];
#pragma unroll
    for (int ks = 0; ks < 16; ++ks) {
        a0[ks] = *(const bf8*)(xp + ks * 32 + lg * 8);
        a1[ks] = *(const bf8*)(xp + 16 * EMB + ks * 32 + lg * 8);
    }
#pragma unroll
    for (int ks = 0; ks < 16; ++ks) {
        asm volatile("" : "+v"(a0[ks]));       // pin: value now asm-defined,
        asm volatile("" : "+v"(a1[ks]));       // cannot be re-loaded from xb
    }

    float Mr[2][4], Sr[2][4];
#pragma unroll
    for (int mf = 0; mf < 2; ++mf)
#pragma unroll
        for (int i = 0; i < 4; ++i) { Mr[mf][i] = -1e38f; Sr[mf][i] = 0.0f; }

    const char* Wbase = (const char*)W;
    f32x4 st[8];                                // staged f32 slab (32 VGPR)

    // 16 lanes per class: lane (c = lane>>4, i = lane&15) holds the 32 f32
    // of class wv*4+c at class-byte offsets i*16 + q*256.
    auto load_st = [&](int ci) {
        const char* src = Wbase + (size_t)ci * (BNF * EMB * 4)
                        + (wv * 4 + (lane >> 4)) * 2048 + (lane & 15) * 16;
#pragma unroll
        for (int q = 0; q < 8; ++q)
            st[q] = *(const f32x4*)(src + q * 256);
    };

    // convert slab in regs -> Bb[b] (swizzled bf16, S/||w|| folded)
    auto conv = [&](int b) {
        float sq = 0.0f;
#pragma unroll
        for (int q = 0; q < 8; ++q)
            sq += st[q][0]*st[q][0] + st[q][1]*st[q][1]
                + st[q][2]*st[q][2] + st[q][3]*st[q][3];
        sq += __shfl_xor(sq, 1); sq += __shfl_xor(sq, 2);
        sq += __shfl_xor(sq, 4); sq += __shfl_xor(sq, 8);   // 16-lane group
        float rn = S_SCALE * rsqrtf(fmaxf(sq, 1e-24f));
        const int cc = wv * 4 + (lane >> 4);   // class row 0..31
        const int i  = lane & 15;
        char* bb = (char*)&Bb[b][0];
#pragma unroll
        for (int q = 0; q < 8; ++q) {
            float v0 = st[q][0] * rn, v1 = st[q][1] * rn;
            float v2 = st[q][2] * rn, v3 = st[q][3] * rn;
            unsigned lo, hi;
            asm("v_cvt_pk_bf16_f32 %0, %1, %2" : "=v"(lo) : "v"(v0), "v"(v1));
            asm("v_cvt_pk_bf16_f32 %0, %1, %2" : "=v"(hi) : "v"(v2), "v"(v3));
            int fj = q * 8 + (i >> 1);                     // 16B unit 0..63
            int ad = cc * 1024 + ((fj ^ (cc & 7)) << 4) + ((i & 1) << 3);
            *(uint2*)(bb + ad) = make_uint2(lo, hi);
        }
    };

    // ---- prologue: chunk bc -> Bb[0]; prefetch chunk bc+NBC into regs ----
    load_st(bc);
    conv(0);
    if (bc + NBC < NCHUNK) load_st(bc + NBC);
    asm volatile("s_waitcnt lgkmcnt(0)" ::: "memory");
    __builtin_amdgcn_sched_barrier(0);
    __builtin_amdgcn_s_barrier();
    __builtin_amdgcn_sched_barrier(0);

    int buf = 0;
    for (int ci = bc; ci < NCHUNK; ci += NBC) {
        const int  cn    = ci + NBC;
        const bool hasN  = cn < NCHUNK;
        const bool hasNN = cn + NBC < NCHUNK;

        f4 acc00, acc01, acc10, acc11;
#pragma unroll
        for (int i = 0; i < 4; ++i) {
            acc00[i] = 0.0f; acc01[i] = 0.0f;
            acc10[i] = 0.0f; acc11[i] = 0.0f;
        }
        const char* BB = (const char*)&Bb[buf][0];

        auto kloop = [&]() {
            __builtin_amdgcn_s_setprio(1);
#pragma unroll
            for (int ks = 0; ks < 16; ++ks) {
                int sx = (((ks * 4 + lg) ^ (l15 & 7)) << 4);
                bf8 b0 = *(const bf8*)(BB + l15 * 1024 + sx);
                bf8 b1 = *(const bf8*)(BB + (16 + l15) * 1024 + sx);
                acc00 = __builtin_amdgcn_mfma_f32_16x16x32_bf16(a0[ks], b0, acc00, 0, 0, 0);
                acc01 = __builtin_amdgcn_mfma_f32_16x16x32_bf16(a0[ks], b1, acc01, 0, 0, 0);
                acc10 = __builtin_amdgcn_mfma_f32_16x16x32_bf16(a1[ks], b0, acc10, 0, 0, 0);
                acc11 = __builtin_amdgcn_mfma_f32_16x16x32_bf16(a1[ks], b1, acc11, 0, 0, 0);
            }
            __builtin_amdgcn_s_setprio(0);
        };

        // ---- stagger: odd waves conv-first, even waves kloop-first ----
        if (wv & 1) {
            if (hasN) { conv(buf ^ 1); if (hasNN) load_st(cn + NBC); }
            kloop();
        } else {
            kloop();
            if (hasN) { conv(buf ^ 1); if (hasNN) load_st(cn + NBC); }
        }

        // ---- epilogue: logits ARE acc -> per-lane online (M,S) ----
#pragma unroll
        for (int i = 0; i < 4; ++i) {
            float v0 = acc00[i], v1 = acc01[i];
            float pm = fmaxf(v0, v1);
            float nM = fmaxf(Mr[0][i], pm);
            Sr[0][i] = Sr[0][i] * __expf(Mr[0][i] - nM)
                     + __expf(v0 - nM) + __expf(v1 - nM);
            Mr[0][i] = nM;
            float w0 = acc10[i], w1 = acc11[i];
            float qm = fmaxf(w0, w1);
            float nN = fmaxf(Mr[1][i], qm);
            Sr[1][i] = Sr[1][i] * __expf(Mr[1][i] - nN)
                     + __expf(w0 - nN) + __expf(w1 - nN);
            Mr[1][i] = nN;
        }

        asm volatile("s_waitcnt lgkmcnt(0)" ::: "memory");  // conv writes done
        __builtin_amdgcn_sched_barrier(0);
        __builtin_amdgcn_s_barrier();       // Bb[buf^1] ready, Bb[buf] consumed
        __builtin_amdgcn_sched_barrier(0);
        buf ^= 1;
    }

    // ---- merge (M,S) across the 16 column-lanes, one write per row ----
#pragma unroll
    for (int mf = 0; mf < 2; ++mf)
#pragma unroll
        for (int i = 0; i < 4; ++i) {
            float M = Mr[mf][i], S = Sr[mf][i];
#pragma unroll
            for (int d = 1; d < 16; d <<= 1) {
                float oM = __shfl_xor(M, d), oS = __shfl_xor(S, d);
                float nM = fmaxf(M, oM);
                S = S * __expf(M - nM) + oS * __expf(oM - nM);
                M = nM;
            }
            if (l15 == 0) {
                int m = rg * 256 + wv * 32 + mf * 16 + lg * 4 + i;
                pms[(size_t)bc * BATCH + m] = make_float2(M, S);
            }
        }
}

// ---------------------------------------------------------------------------
// k_red: merge 2 column-partials per slot, coalesced. part[b][m].
// ---------------------------------------------------------------------------
__global__ __launch_bounds__(512) void k_red(const float2* __restrict__ pms,
                                             float2* __restrict__ part) {
    int t = threadIdx.x, b = blockIdx.x;
    float2 v0 = pms[(size_t)(b * 2)     * BATCH + t];
    float2 v1 = pms[(size_t)(b * 2 + 1) * BATCH + t];
    float M = fmaxf(v0.x, v1.x);
    float S = v0.y * __expf(v0.x - M) + v1.y * __expf(v1.x - M);
    part[b * BATCH + t] = make_float2(M, S);
}

// ---------------------------------------------------------------------------
// k_fin: merge 64 partials per row, patch label col, loss, mean.
// ---------------------------------------------------------------------------
__global__ __launch_bounds__(512) void k_fin(const float2* __restrict__ part,
                                             const float* __restrict__ tcos,
                                             const float* __restrict__ tphi,
                                             float* __restrict__ out) {
    int t = threadIdx.x;
    float M = -1e38f, S = 0.f;
#pragma unroll 4
    for (int b = 0; b < RBLK; ++b) {
        float2 v = part[b * BATCH + t];
        float nM = fmaxf(M, v.x);
        S = S * __expf(M - nM) + v.y * __expf(v.x - nM);
        M = nM;
    }
    float Sc = S - __expf(tcos[t] - M) + __expf(tphi[t] - M);
    Sc = fmaxf(Sc, 1e-30f);
    float loss = M + logf(Sc) - tphi[t];
#pragma unroll
    for (int d = 1; d < 64; d <<= 1) loss += __shfl_xor(loss, d);
    __shared__ float wred[8];
    if ((t & 63) == 0) wred[t >> 6] = loss;
    __syncthreads();
    if (t == 0) {
        float s = 0.f;
        for (int w = 0; w < 8; ++w) s += wred[w];
        out[0] = s / (float)BATCH;
    }
}

extern "C" void kernel_launch(void* const* d_in, const int* in_sizes, int n_in,
                              void* d_out, int out_size, void* d_ws, size_t ws_size,
                              hipStream_t stream) {
    const float*     x     = (const float*)d_in[0];
    const long long* label = (const long long*)d_in[1];
    const float*     W     = (const float*)d_in[2];
    float*           out   = (float*)d_out;

    // workspace layout (~1.4 MB)
    char* ws = (char*)d_ws;
    unsigned short* xb   = (unsigned short*)ws;              // 524288
    float*          tcos = (float*)(ws + 524288);            // 2048
    float*          tphi = (float*)(ws + 526336);            // 2048
    float2*         pms  = (float2*)(ws + 528384);           // 128*512*8 = 524288
    float2*         part = (float2*)(ws + 1052672);          // 64*512*8 = 262144

    k_pre  <<<BATCH / 4, 256, 0, stream>>>(x, W, label, xb, tcos, tphi);
    k_fused<<<GRID_F,    512, 0, stream>>>(W, xb, pms);
    k_red  <<<RBLK,      512, 0, stream>>>(pms, part);
    k_fin  <<<1,         512, 0, stream>>>(part, tcos, tphi, out);
}